// Round 9
// baseline (203.443 us; speedup 1.0000x reference)
//
#include <hip/hip_runtime.h>

typedef __bf16 bf16;
typedef bf16 bf16x8 __attribute__((ext_vector_type(8)));
typedef bf16 bf16x4 __attribute__((ext_vector_type(4)));
typedef float f32x4 __attribute__((ext_vector_type(4)));

#define SEQ 4096
#define SQQ 1024
#define NH  6
#define HD  64

#define MFMA16 __builtin_amdgcn_mfma_f32_16x16x32_bf16

typedef const __attribute__((address_space(1))) void gvoid_t;
typedef __attribute__((address_space(3))) void svoid_t;

__device__ __forceinline__ void gload16(const bf16* g, bf16* l) {
  __builtin_amdgcn_global_load_lds((gvoid_t*)g, (svoid_t*)l, 16, 0, 0);
}

// -------------------------------------------------------------------------
// K0: prep — Wq [192][1152] -> Wqt bf16 [1152 n][192 k];
//            Wp [384][384]  -> Wpt bf16 [384 n][384 k];
//            X f32 -> Xb bf16 (vec8)
// -------------------------------------------------------------------------
__global__ __launch_bounds__(256) void k_prep(
    const float* __restrict__ X, const float* __restrict__ Wq,
    const float* __restrict__ Wp,
    bf16* __restrict__ Xb, bf16* __restrict__ Wqt, bf16* __restrict__ Wpt)
{
  int i = blockIdx.x * 256 + threadIdx.x;
  const int NW = 1152 * 192;
  const int NP = 384 * 384;
  if (i < NW) {
    int n = i / 192, k = i - n * 192;
    Wqt[i] = (bf16)Wq[k * 1152 + n];
  } else if (i < NW + NP) {
    int j = i - NW;
    int n = j / 384, k = j - n * 384;
    Wpt[j] = (bf16)Wp[k * 384 + n];
  } else {
    int v = i - (NW + NP);
    if (v < 393216) {
      f32x4 x0 = *(const f32x4*)&X[(size_t)v * 8];
      f32x4 x1 = *(const f32x4*)&X[(size_t)v * 8 + 4];
      bf16x8 h;
#pragma unroll
      for (int e = 0; e < 4; ++e) { h[e] = (bf16)x0[e]; h[4 + e] = (bf16)x1[e]; }
      *(bf16x8*)&Xb[(size_t)v * 8] = h;
    }
  }
}

// -------------------------------------------------------------------------
// K1: QKV GEMM, bf16 MFMA, direct global fragments (L2-local), 2-deep
// register prefetch, zero in-loop barriers.
// DELTA R9: __launch_bounds__(256,4) — force VGPR<=128 (was 132) to get
// 4 waves/SIMD (16 waves/CU, from 12). Kernel is latency-bound on L2
// fragment loads (~1 us of MFMA in ~40 us) — +33% wave-level hiding.
// -------------------------------------------------------------------------
__global__ __launch_bounds__(256, 4) void k_qkv(
    const bf16* __restrict__ Xb, const bf16* __restrict__ Wt,
    const float* __restrict__ bias,
    bf16* __restrict__ Kb, bf16* __restrict__ Vt, bf16* __restrict__ Qp)
{
  __shared__ __attribute__((aligned(16))) bf16 Qs[128 * 136];
  const int tid = threadIdx.x;
  const int w = tid >> 6, lane = tid & 63, quad = lane >> 4, l16 = lane & 15;
  const int wm = w & 1, wn = w >> 1;
  const int m0 = blockIdx.x * 128, n0 = blockIdx.y * 128;
  const int c3 = n0 / 384, nb = n0 - c3 * 384, b = m0 >> 12;

  const bf16* Arow = Xb + (size_t)(m0 + wm * 64 + l16) * 192 + quad * 8;
  const bf16* Brow = Wt + (size_t)(n0 + wn * 64 + l16) * 192 + quad * 8;

  f32x4 acc[4][4] = {};
  bf16x8 af[2][4], bw[2][4];
#pragma unroll
  for (int p = 0; p < 2; ++p)
#pragma unroll
    for (int t = 0; t < 4; ++t) {
      af[p][t] = *(const bf16x8*)(Arow + t * 16 * 192 + p * 32);
      bw[p][t] = *(const bf16x8*)(Brow + t * 16 * 192 + p * 32);
    }
#pragma unroll
  for (int kk = 0; kk < 6; ++kk) {
    const int s = kk & 1;
    if (c3 == 2) {
#pragma unroll
      for (int mt = 0; mt < 4; ++mt)
#pragma unroll
        for (int nt = 0; nt < 4; ++nt)
          acc[mt][nt] = MFMA16(af[s][mt], bw[s][nt], acc[mt][nt], 0, 0, 0);
    } else {
#pragma unroll
      for (int mt = 0; mt < 4; ++mt)
#pragma unroll
        for (int nt = 0; nt < 4; ++nt)
          acc[mt][nt] = MFMA16(bw[s][nt], af[s][mt], acc[mt][nt], 0, 0, 0);
    }
    if (kk < 4) {
      const int ko = (kk + 2) * 32;
#pragma unroll
      for (int t = 0; t < 4; ++t) {
        af[s][t] = *(const bf16x8*)(Arow + t * 16 * 192 + ko);
        bw[s][t] = *(const bf16x8*)(Brow + t * 16 * 192 + ko);
      }
    }
  }

  if (c3 == 2) {
    float bn[4];
#pragma unroll
    for (int nt = 0; nt < 4; ++nt) bn[nt] = bias[n0 + wn * 64 + nt * 16 + l16];
#pragma unroll
    for (int mt = 0; mt < 4; ++mt) {
      int sb = (m0 & 4095) + wm * 64 + mt * 16 + quad * 4;
#pragma unroll
      for (int nt = 0; nt < 4; ++nt) {
        int dcol = nb + wn * 64 + nt * 16 + l16;
        int h = dcol >> 6, dd = dcol & 63;
        bf16x4 pv;
#pragma unroll
        for (int r = 0; r < 4; ++r) pv[r] = (bf16)(acc[mt][nt][r] + bn[nt]);
        *(bf16x4*)&Vt[((size_t)(b * NH + h) * HD + dd) * SEQ + sb] = pv;
      }
    }
  } else if (c3 == 1) {
    f32x4 bv[4];
#pragma unroll
    for (int nt = 0; nt < 4; ++nt)
      bv[nt] = *(const f32x4*)&bias[n0 + wn * 64 + nt * 16 + quad * 4];
#pragma unroll
    for (int mt = 0; mt < 4; ++mt) {
      int s = (m0 & 4095) + wm * 64 + mt * 16 + l16;
#pragma unroll
      for (int nt = 0; nt < 4; ++nt) {
        int ncol = nb + wn * 64 + nt * 16 + quad * 4;
        int h = ncol >> 6, dd = ncol & 63;
        bf16x4 pv;
#pragma unroll
        for (int r = 0; r < 4; ++r) pv[r] = (bf16)(acc[mt][nt][r] + bv[nt][r]);
        *(bf16x4*)&Kb[((size_t)(b * NH + h) * SEQ + s) * HD + dd] = pv;
      }
    }
  } else {
    f32x4 bv[4];
#pragma unroll
    for (int nt = 0; nt < 4; ++nt)
      bv[nt] = *(const f32x4*)&bias[n0 + wn * 64 + nt * 16 + quad * 4];
#pragma unroll
    for (int mt = 0; mt < 4; ++mt) {
      int ml = wm * 64 + mt * 16 + l16;
#pragma unroll
      for (int nt = 0; nt < 4; ++nt) {
        int ncl = wn * 64 + nt * 16 + quad * 4;
        bf16x4 pv;
#pragma unroll
        for (int r = 0; r < 4; ++r) pv[r] = (bf16)(acc[mt][nt][r] + bv[nt][r]);
        *(bf16x4*)&Qs[ml * 136 + ncl] = pv;
      }
    }
    __syncthreads();
    const int wq = tid >> 3, cg = tid & 7;
    const int hq = (m0 & 4095) >> 7;
#pragma unroll
    for (int j8 = 0; j8 < 2; ++j8) {
      int co = cg * 16 + j8 * 8;
      bf16x8 q0 = *(const bf16x8*)&Qs[(2 * wq)     * 136 + co];
      bf16x8 q1 = *(const bf16x8*)&Qs[(2 * wq + 1) * 136 + co];
      bf16x8 q2 = *(const bf16x8*)&Qs[(64 + 2 * wq)     * 136 + co];
      bf16x8 q3 = *(const bf16x8*)&Qs[(64 + 2 * wq + 1) * 136 + co];
      bf16x8 o;
#pragma unroll
      for (int e = 0; e < 8; ++e) {
        float mx = fmaxf(fmaxf((float)q0[e], (float)q1[e]),
                         fmaxf((float)q2[e], (float)q3[e]));
        o[e] = (bf16)(mx * 0.180336880111f);   // 0.125 * log2(e)
      }
      int gc = nb + co;
      int h = gc >> 6, d0 = gc & 63;
      *(bf16x8*)&Qp[((size_t)(b * NH + h) * SQQ + hq * 32 + wq) * HD + d0] = o;
    }
  }
}

// -------------------------------------------------------------------------
// K3: attention — EXACT R6 version (proven 42.6 us): 4 waves/block, 32 q/wave,
// double-buffered KV LDS via global_load_lds, XOR-swizzled conflict-free
// reads, S^T=K.Q^T, no max-stabilization, K-split 4. Grid (24, 8, 4), 256 thr.
// -------------------------------------------------------------------------
__global__ __launch_bounds__(256) void k_attn(
    const bf16* __restrict__ Qp, const bf16* __restrict__ Kb,
    const bf16* __restrict__ Vt, bf16* __restrict__ Op, float* __restrict__ lp)
{
  __shared__ __attribute__((aligned(16))) bf16 KVs0[2][64 * 64];  // K [kpos][d^]
  __shared__ __attribute__((aligned(16))) bf16 KVs1[2][64 * 64];  // V^T [d][kpos^]
  __shared__ __attribute__((aligned(16))) bf16 Pq[4][32 * 72];    // per-wave P

  const int tid = threadIdx.x;
  const int w = tid >> 6, lane = tid & 63, quad = lane >> 4, l16 = lane & 15;
  const int bh = blockIdx.x, qb = blockIdx.y, ks = blockIdx.z;
  const int q0 = qb * 128 + w * 32;

  const bf16* Qg = Qp + (size_t)bh * SQQ * HD;
  const bf16* Kg = Kb + (size_t)bh * SEQ * HD;
  const bf16* Vg = Vt + (size_t)bh * HD * SEQ;

  bf16x8 qf[2][2];
#pragma unroll
  for (int qt = 0; qt < 2; ++qt)
#pragma unroll
    for (int dk = 0; dk < 2; ++dk)
      qf[qt][dk] = *(const bf16x8*)&Qg[(size_t)(q0 + qt * 16 + l16) * HD + dk * 32 + quad * 8];

  const int swz = l16 & 7;
  const int sw0 = ((quad ^ swz) * 16);
  const int sw1 = (((quad + 4) ^ swz) * 16);
  const int sr = lane >> 3;          // 0..7
  const int sc = (lane & 7) ^ sr;    // XOR-permuted source chunk

  const bf16* src;
  bf16 *dstA, *dstB;
  size_t rstride, step;
  if (w < 2) {
    src = Kg + (size_t)(ks * 1024 + w * 32 + sr) * HD + sc * 8;
    dstA = &KVs0[0][(w * 32) * 64];
    dstB = &KVs0[1][(w * 32) * 64];
    rstride = 8 * HD;  step = 64 * HD;
  } else {
    src = Vg + (size_t)((w - 2) * 32 + sr) * SEQ + ks * 1024 + sc * 8;
    dstA = &KVs1[0][((w - 2) * 32) * 64];
    dstB = &KVs1[1][((w - 2) * 32) * 64];
    rstride = 8 * SEQ; step = 64;
  }

#pragma unroll
  for (int c = 0; c < 4; ++c) gload16(src + c * rstride, dstA + c * 8 * 64);

  f32x4 lac[2] = {};
  f32x4 accO[4][2] = {};
  bf16* PqW = &Pq[w][0];

  for (int it = 0; it < 16; ++it) {
    const int p = it & 1;
    __asm__ volatile("s_waitcnt vmcnt(0)" ::: "memory");
    __syncthreads();
    if (it < 15) {
      const bf16* s2 = src + (size_t)(it + 1) * step;
      bf16* dn = p ? dstA : dstB;
#pragma unroll
      for (int c = 0; c < 4; ++c) gload16(s2 + c * rstride, dn + c * 8 * 64);
    }

    const char* Kbase = (const char*)&KVs0[p][0];
    const char* Vbase = (const char*)&KVs1[p][0];

#pragma unroll
    for (int nt = 0; nt < 4; ++nt) {
      const char* rb = Kbase + (nt * 16 + l16) * 128;
      bf16x8 k0 = *(const bf16x8*)(rb + sw0);
      bf16x8 k1 = *(const bf16x8*)(rb + sw1);
#pragma unroll
      for (int qt = 0; qt < 2; ++qt) {
        f32x4 s = {};
        s = MFMA16(k0, qf[qt][0], s, 0, 0, 0);
        s = MFMA16(k1, qf[qt][1], s, 0, 0, 0);
        f32x4 pv;
#pragma unroll
        for (int e = 0; e < 4; ++e) pv[e] = __builtin_amdgcn_exp2f(s[e]);
        lac[qt] += pv;
        bf16x4 pb4;
#pragma unroll
        for (int e = 0; e < 4; ++e) pb4[e] = (bf16)pv[e];
        *(bf16x4*)&PqW[(qt * 16 + l16) * 72 + nt * 16 + quad * 4] = pb4;
      }
    }
    __asm__ volatile("s_waitcnt lgkmcnt(0)" ::: "memory");

#pragma unroll
    for (int ck = 0; ck < 2; ++ck) {
      bf16x8 bp0 = *(const bf16x8*)&PqW[(l16) * 72 + ck * 32 + quad * 8];
      bf16x8 bp1 = *(const bf16x8*)&PqW[(16 + l16) * 72 + ck * 32 + quad * 8];
      const int swc = ck ? sw1 : sw0;
#pragma unroll
      for (int dt = 0; dt < 4; ++dt) {
        bf16x8 av = *(const bf16x8*)(Vbase + (dt * 16 + l16) * 128 + swc);
        accO[dt][0] = MFMA16(av, bp0, accO[dt][0], 0, 0, 0);
        accO[dt][1] = MFMA16(av, bp1, accO[dt][1], 0, 0, 0);
      }
    }
  }

#pragma unroll
  for (int qt = 0; qt < 2; ++qt) {
    float lt = lac[qt][0] + lac[qt][1] + lac[qt][2] + lac[qt][3];
    lt += __shfl_xor(lt, 16);
    lt += __shfl_xor(lt, 32);
    if (lane < 16)
      lp[(size_t)(ks * 24 + bh) * SQQ + q0 + qt * 16 + l16] = lt;
#pragma unroll
    for (int dt = 0; dt < 4; ++dt) {
      bf16x4 ov;
#pragma unroll
      for (int r = 0; r < 4; ++r) ov[r] = (bf16)accO[dt][qt][r];
      *(bf16x4*)&Op[((size_t)(ks * 24 + bh) * SQQ + q0 + qt * 16 + l16) * HD + dt * 16 + quad * 4] = ov;
    }
  }
}

// -------------------------------------------------------------------------
// K4: merge 4 K-split partials -> Obb bf16 [b*1024+q][h*64+d], vec8
// -------------------------------------------------------------------------
__global__ __launch_bounds__(256) void k_merge(
    const bf16* __restrict__ Op, const float* __restrict__ lp,
    bf16* __restrict__ Ob)
{
  int t = blockIdx.x * 256 + threadIdx.x;          // 196608 total
  int d8 = t & 7, q = (t >> 3) & 1023, bh = t >> 13;
  float l = 0.f;
  float s[8] = {};
#pragma unroll
  for (int sp = 0; sp < 4; ++sp) {
    l += lp[(size_t)(sp * 24 + bh) * SQQ + q];
    bf16x8 v = *(const bf16x8*)&Op[((size_t)(sp * 24 + bh) * SQQ + q) * HD + d8 * 8];
#pragma unroll
    for (int e = 0; e < 8; ++e) s[e] += (float)v[e];
  }
  float inv = 1.0f / l;
  int b = bh / NH, h = bh - b * NH;
  bf16x8 o;
#pragma unroll
  for (int e = 0; e < 8; ++e) o[e] = (bf16)(s[e] * inv);
  *(bf16x8*)&Ob[((size_t)(b * SQQ + q)) * 384 + h * HD + d8 * 8] = o;
}

// -------------------------------------------------------------------------
// K5: proj GEMM, bf16 MFMA, swapped orientation -> f32x4 stores.
// Obb[4096x384] @ Wpt[384 n][384 k] + bias. Grid (32, 6), 128 thr.
// -------------------------------------------------------------------------
__global__ __launch_bounds__(128) void k_proj(
    const bf16* __restrict__ A, const bf16* __restrict__ Wt,
    const float* __restrict__ bias, float* __restrict__ out)
{
  __shared__ __attribute__((aligned(16))) bf16 As[128 * 40];
  __shared__ __attribute__((aligned(16))) bf16 Bs[64 * 40];
  const int tid = threadIdx.x;
  const int w = tid >> 6, lane = tid & 63, quad = lane >> 4, l16 = lane & 15;
  const int m0 = blockIdx.x * 128, n0 = blockIdx.y * 64;

  f32x4 acc[4][4] = {};

  for (int kc = 0; kc < 12; ++kc) {
    const int k0 = kc * 32;
    bf16x8 a4[4], b4[2];
#pragma unroll
    for (int c = 0; c < 4; ++c) {
      int ci = c * 128 + tid, rw = ci >> 2, c8 = ci & 3;
      a4[c] = *(const bf16x8*)&A[(size_t)(m0 + rw) * 384 + k0 + c8 * 8];
    }
#pragma unroll
    for (int c = 0; c < 2; ++c) {
      int ci = c * 128 + tid, rw = ci >> 2, c8 = ci & 3;
      b4[c] = *(const bf16x8*)&Wt[(size_t)(n0 + rw) * 384 + k0 + c8 * 8];
    }
    __syncthreads();
#pragma unroll
    for (int c = 0; c < 4; ++c) {
      int ci = c * 128 + tid, rw = ci >> 2, c8 = ci & 3;
      *(bf16x8*)&As[rw * 40 + c8 * 8] = a4[c];
    }
#pragma unroll
    for (int c = 0; c < 2; ++c) {
      int ci = c * 128 + tid, rw = ci >> 2, c8 = ci & 3;
      *(bf16x8*)&Bs[rw * 40 + c8 * 8] = b4[c];
    }
    __syncthreads();
    bf16x8 af[4], bw[4];
#pragma unroll
    for (int t = 0; t < 4; ++t) {
      af[t] = *(const bf16x8*)&As[(w * 64 + t * 16 + l16) * 40 + quad * 8];
      bw[t] = *(const bf16x8*)&Bs[(t * 16 + l16) * 40 + quad * 8];
    }
#pragma unroll
    for (int mt = 0; mt < 4; ++mt)
#pragma unroll
      for (int nt = 0; nt < 4; ++nt)
        acc[mt][nt] = MFMA16(bw[nt], af[mt], acc[mt][nt], 0, 0, 0);
  }

  f32x4 bv[4];
#pragma unroll
  for (int nt = 0; nt < 4; ++nt)
    bv[nt] = *(const f32x4*)&bias[n0 + nt * 16 + quad * 4];
#pragma unroll
  for (int mt = 0; mt < 4; ++mt) {
    int m = m0 + w * 64 + mt * 16 + l16;
#pragma unroll
    for (int nt = 0; nt < 4; ++nt) {
      f32x4 o = acc[mt][nt] + bv[nt];
      *(f32x4*)&out[(size_t)m * 384 + n0 + nt * 16 + quad * 4] = o;
    }
  }
}

// -------------------------------------------------------------------------
// ws layout (bytes):
//   Kb    @ 0         12582912   (qkv -> attn)
//   Vt    @ 12582912  12582912   (qkv -> attn)
//   Qp    @ 25165824   3145728   (qkv -> attn)
//   Wqt   @ 28311552    442368   (prep -> qkv)
//   Wpt   @ 28753920    294912   (prep -> proj)
//   lp    @ 29048832    393216   (attn -> merge)
//   Obb   @ 29442048   3145728   (merge -> proj)
//   Xb    @ 32587776   6291456   (prep -> qkv, dead after)
//   Opart @ 32587776  12582912   (attn -> merge; overlays Xb)
// total 45170688
// -------------------------------------------------------------------------
extern "C" void kernel_launch(void* const* d_in, const int* in_sizes, int n_in,
                              void* d_out, int out_size, void* d_ws, size_t ws_size,
                              hipStream_t stream)
{
  (void)in_sizes; (void)n_in; (void)out_size; (void)ws_size;
  const float* X  = (const float*)d_in[0];
  const float* Wq = (const float*)d_in[1];
  const float* qb = (const float*)d_in[2];
  const float* Wp = (const float*)d_in[3];
  const float* pb = (const float*)d_in[4];
  float* out = (float*)d_out;

  char* ws = (char*)d_ws;
  bf16*  Kb    = (bf16*)(ws);
  bf16*  Vt    = (bf16*)(ws + 12582912);
  bf16*  Qp    = (bf16*)(ws + 25165824);
  bf16*  Wqt   = (bf16*)(ws + 28311552);
  bf16*  Wpt   = (bf16*)(ws + 28753920);
  float* lpart = (float*)(ws + 29048832);
  bf16*  Obb   = (bf16*)(ws + 29442048);
  bf16*  Xb    = (bf16*)(ws + 32587776);
  bf16*  Opart = (bf16*)(ws + 32587776);   // overlays Xb (dead after k_qkv)

  k_prep <<<2976, 256, 0, stream>>>(X, Wq, Wp, Xb, Wqt, Wpt);
  k_qkv  <<<dim3(128, 9), 256, 0, stream>>>(Xb, Wqt, qb, Kb, Vt, Qp);
  k_attn <<<dim3(24, 8, 4), 256, 0, stream>>>(Qp, Kb, Vt, Opart, lpart);
  k_merge<<<768, 256, 0, stream>>>(Opart, lpart, Obb);
  k_proj <<<dim3(32, 6), 128, 0, stream>>>(Obb, Wpt, pb, out);
}

// Round 10
// 165.579 us; speedup vs baseline: 1.2287x; 1.2287x over previous
//
#include <hip/hip_runtime.h>

typedef __bf16 bf16;
typedef bf16 bf16x8 __attribute__((ext_vector_type(8)));
typedef bf16 bf16x4 __attribute__((ext_vector_type(4)));
typedef float f32x4 __attribute__((ext_vector_type(4)));

#define SEQ 4096
#define SQQ 1024
#define NH  6
#define HD  64

#define MFMA16 __builtin_amdgcn_mfma_f32_16x16x32_bf16

typedef const __attribute__((address_space(1))) void gvoid_t;
typedef __attribute__((address_space(3))) void svoid_t;

__device__ __forceinline__ void gload16(const bf16* g, bf16* l) {
  __builtin_amdgcn_global_load_lds((gvoid_t*)g, (svoid_t*)l, 16, 0, 0);
}

// -------------------------------------------------------------------------
// K0: prep — Wq [192][1152] -> Wqt bf16 [1152 n][192 k];
//            Wp [384][384]  -> Wpt bf16 [384 n][384 k];
//            X f32 -> Xb bf16 (vec8)
// -------------------------------------------------------------------------
__global__ __launch_bounds__(256) void k_prep(
    const float* __restrict__ X, const float* __restrict__ Wq,
    const float* __restrict__ Wp,
    bf16* __restrict__ Xb, bf16* __restrict__ Wqt, bf16* __restrict__ Wpt)
{
  int i = blockIdx.x * 256 + threadIdx.x;
  const int NW = 1152 * 192;
  const int NP = 384 * 384;
  if (i < NW) {
    int n = i / 192, k = i - n * 192;
    Wqt[i] = (bf16)Wq[k * 1152 + n];
  } else if (i < NW + NP) {
    int j = i - NW;
    int n = j / 384, k = j - n * 384;
    Wpt[j] = (bf16)Wp[k * 384 + n];
  } else {
    int v = i - (NW + NP);
    if (v < 393216) {
      f32x4 x0 = *(const f32x4*)&X[(size_t)v * 8];
      f32x4 x1 = *(const f32x4*)&X[(size_t)v * 8 + 4];
      bf16x8 h;
#pragma unroll
      for (int e = 0; e < 4; ++e) { h[e] = (bf16)x0[e]; h[4 + e] = (bf16)x1[e]; }
      *(bf16x8*)&Xb[(size_t)v * 8] = h;
    }
  }
}

// -------------------------------------------------------------------------
// K1: QKV GEMM, bf16 MFMA, direct global fragments (L2-local), 2-deep
// register prefetch, zero in-loop barriers.
// R10 DELTA: tile 128m x 64n (was 128x128) -> acc 32 VGPR/wave (was 64),
// natural VGPR ~100-110 -> 4 waves/EU without launch-bounds coercion
// (R9 proved forcing bounds => spill). Grid (128, 18) = 2304 blocks.
// 64-wide n-blocks: c3 AND head h uniform per block (384 = 6*64).
// Epilogues keep b64 stores; Q-pool fusion keeps its 128-row H-pair.
// -------------------------------------------------------------------------
__global__ __launch_bounds__(256) void k_qkv(
    const bf16* __restrict__ Xb, const bf16* __restrict__ Wt,
    const float* __restrict__ bias,
    bf16* __restrict__ Kb, bf16* __restrict__ Vt, bf16* __restrict__ Qp)
{
  __shared__ __attribute__((aligned(16))) bf16 Qs[128 * 72];
  const int tid = threadIdx.x;
  const int w = tid >> 6, lane = tid & 63, quad = lane >> 4, l16 = lane & 15;
  const int wm = w & 1, wn = w >> 1;          // 2m x 2n wave grid
  const int m0 = blockIdx.x * 128, n0 = blockIdx.y * 64;
  const int c3 = n0 / 384, nb = n0 - c3 * 384, b = m0 >> 12;
  const int h = nb >> 6;                      // head, uniform per block

  const bf16* Arow = Xb + (size_t)(m0 + wm * 64 + l16) * 192 + quad * 8;
  const bf16* Brow = Wt + (size_t)(n0 + wn * 32 + l16) * 192 + quad * 8;

  f32x4 acc[4][2] = {};
  bf16x8 af[2][4], bw[2][2];
#pragma unroll
  for (int p = 0; p < 2; ++p) {
#pragma unroll
    for (int t = 0; t < 4; ++t)
      af[p][t] = *(const bf16x8*)(Arow + t * 16 * 192 + p * 32);
#pragma unroll
    for (int u = 0; u < 2; ++u)
      bw[p][u] = *(const bf16x8*)(Brow + u * 16 * 192 + p * 32);
  }
#pragma unroll
  for (int kk = 0; kk < 6; ++kk) {
    const int s = kk & 1;
    if (c3 == 2) {
#pragma unroll
      for (int mt = 0; mt < 4; ++mt)
#pragma unroll
        for (int nt = 0; nt < 2; ++nt)
          acc[mt][nt] = MFMA16(af[s][mt], bw[s][nt], acc[mt][nt], 0, 0, 0);
    } else {
#pragma unroll
      for (int mt = 0; mt < 4; ++mt)
#pragma unroll
        for (int nt = 0; nt < 2; ++nt)
          acc[mt][nt] = MFMA16(bw[s][nt], af[s][mt], acc[mt][nt], 0, 0, 0);
    }
    if (kk < 4) {
      const int ko = (kk + 2) * 32;
#pragma unroll
      for (int t = 0; t < 4; ++t)
        af[s][t] = *(const bf16x8*)(Arow + t * 16 * 192 + ko);
#pragma unroll
      for (int u = 0; u < 2; ++u)
        bw[s][u] = *(const bf16x8*)(Brow + u * 16 * 192 + ko);
    }
  }

  if (c3 == 2) {
    // normal: D[row=m=s (quad*4+r)][col=n=d (l16)] -> V^T[d][s] b64 stores
    float bn[2];
#pragma unroll
    for (int nt = 0; nt < 2; ++nt) bn[nt] = bias[n0 + wn * 32 + nt * 16 + l16];
#pragma unroll
    for (int mt = 0; mt < 4; ++mt) {
      int sb = (m0 & 4095) + wm * 64 + mt * 16 + quad * 4;
#pragma unroll
      for (int nt = 0; nt < 2; ++nt) {
        int dd = wn * 32 + nt * 16 + l16;
        bf16x4 pv;
#pragma unroll
        for (int r = 0; r < 4; ++r) pv[r] = (bf16)(acc[mt][nt][r] + bn[nt]);
        *(bf16x4*)&Vt[((size_t)(b * NH + h) * HD + dd) * SEQ + sb] = pv;
      }
    }
  } else if (c3 == 1) {
    // swapped: D[row=n (quad*4+r)][col=m (l16)] -> K[bh][s][d] b64 stores
    f32x4 bv[2];
#pragma unroll
    for (int nt = 0; nt < 2; ++nt)
      bv[nt] = *(const f32x4*)&bias[n0 + wn * 32 + nt * 16 + quad * 4];
#pragma unroll
    for (int mt = 0; mt < 4; ++mt) {
      int s = (m0 & 4095) + wm * 64 + mt * 16 + l16;
#pragma unroll
      for (int nt = 0; nt < 2; ++nt) {
        int dd = wn * 32 + nt * 16 + quad * 4;
        bf16x4 pv;
#pragma unroll
        for (int r = 0; r < 4; ++r) pv[r] = (bf16)(acc[mt][nt][r] + bv[nt][r]);
        *(bf16x4*)&Kb[((size_t)(b * NH + h) * SEQ + s) * HD + dd] = pv;
      }
    }
  } else {
    // Q: swapped -> LDS tile (128 rows x 64 cols of this head) -> 2x2 pool
    f32x4 bv[2];
#pragma unroll
    for (int nt = 0; nt < 2; ++nt)
      bv[nt] = *(const f32x4*)&bias[n0 + wn * 32 + nt * 16 + quad * 4];
#pragma unroll
    for (int mt = 0; mt < 4; ++mt) {
      int ml = wm * 64 + mt * 16 + l16;
#pragma unroll
      for (int nt = 0; nt < 2; ++nt) {
        int ncl = wn * 32 + nt * 16 + quad * 4;
        bf16x4 pv;
#pragma unroll
        for (int r = 0; r < 4; ++r) pv[r] = (bf16)(acc[mt][nt][r] + bv[nt][r]);
        *(bf16x4*)&Qs[ml * 72 + ncl] = pv;
      }
    }
    __syncthreads();
    // pool: thread t -> wq = t>>3 (32 pooled cols), cg = t&7 (8 d-groups x 8)
    const int wq = tid >> 3, cg = tid & 7;
    const int hq = (m0 & 4095) >> 7;
    const int co = cg * 8;
    bf16x8 q0 = *(const bf16x8*)&Qs[(2 * wq)     * 72 + co];
    bf16x8 q1 = *(const bf16x8*)&Qs[(2 * wq + 1) * 72 + co];
    bf16x8 q2 = *(const bf16x8*)&Qs[(64 + 2 * wq)     * 72 + co];
    bf16x8 q3 = *(const bf16x8*)&Qs[(64 + 2 * wq + 1) * 72 + co];
    bf16x8 o;
#pragma unroll
    for (int e = 0; e < 8; ++e) {
      float mx = fmaxf(fmaxf((float)q0[e], (float)q1[e]),
                       fmaxf((float)q2[e], (float)q3[e]));
      o[e] = (bf16)(mx * 0.180336880111f);   // 0.125 * log2(e)
    }
    *(bf16x8*)&Qp[((size_t)(b * NH + h) * SQQ + hq * 32 + wq) * HD + co] = o;
  }
}

// -------------------------------------------------------------------------
// K3: attention — EXACT R6 version (proven 42.6 us): 4 waves/block, 32 q/wave,
// double-buffered KV LDS via global_load_lds, XOR-swizzled conflict-free
// reads, S^T=K.Q^T, no max-stabilization, K-split 4. Grid (24, 8, 4), 256 thr.
// -------------------------------------------------------------------------
__global__ __launch_bounds__(256) void k_attn(
    const bf16* __restrict__ Qp, const bf16* __restrict__ Kb,
    const bf16* __restrict__ Vt, bf16* __restrict__ Op, float* __restrict__ lp)
{
  __shared__ __attribute__((aligned(16))) bf16 KVs0[2][64 * 64];  // K [kpos][d^]
  __shared__ __attribute__((aligned(16))) bf16 KVs1[2][64 * 64];  // V^T [d][kpos^]
  __shared__ __attribute__((aligned(16))) bf16 Pq[4][32 * 72];    // per-wave P

  const int tid = threadIdx.x;
  const int w = tid >> 6, lane = tid & 63, quad = lane >> 4, l16 = lane & 15;
  const int bh = blockIdx.x, qb = blockIdx.y, ks = blockIdx.z;
  const int q0 = qb * 128 + w * 32;

  const bf16* Qg = Qp + (size_t)bh * SQQ * HD;
  const bf16* Kg = Kb + (size_t)bh * SEQ * HD;
  const bf16* Vg = Vt + (size_t)bh * HD * SEQ;

  bf16x8 qf[2][2];
#pragma unroll
  for (int qt = 0; qt < 2; ++qt)
#pragma unroll
    for (int dk = 0; dk < 2; ++dk)
      qf[qt][dk] = *(const bf16x8*)&Qg[(size_t)(q0 + qt * 16 + l16) * HD + dk * 32 + quad * 8];

  const int swz = l16 & 7;
  const int sw0 = ((quad ^ swz) * 16);
  const int sw1 = (((quad + 4) ^ swz) * 16);
  const int sr = lane >> 3;          // 0..7
  const int sc = (lane & 7) ^ sr;    // XOR-permuted source chunk

  const bf16* src;
  bf16 *dstA, *dstB;
  size_t rstride, step;
  if (w < 2) {
    src = Kg + (size_t)(ks * 1024 + w * 32 + sr) * HD + sc * 8;
    dstA = &KVs0[0][(w * 32) * 64];
    dstB = &KVs0[1][(w * 32) * 64];
    rstride = 8 * HD;  step = 64 * HD;
  } else {
    src = Vg + (size_t)((w - 2) * 32 + sr) * SEQ + ks * 1024 + sc * 8;
    dstA = &KVs1[0][((w - 2) * 32) * 64];
    dstB = &KVs1[1][((w - 2) * 32) * 64];
    rstride = 8 * SEQ; step = 64;
  }

#pragma unroll
  for (int c = 0; c < 4; ++c) gload16(src + c * rstride, dstA + c * 8 * 64);

  f32x4 lac[2] = {};
  f32x4 accO[4][2] = {};
  bf16* PqW = &Pq[w][0];

  for (int it = 0; it < 16; ++it) {
    const int p = it & 1;
    __asm__ volatile("s_waitcnt vmcnt(0)" ::: "memory");
    __syncthreads();
    if (it < 15) {
      const bf16* s2 = src + (size_t)(it + 1) * step;
      bf16* dn = p ? dstA : dstB;
#pragma unroll
      for (int c = 0; c < 4; ++c) gload16(s2 + c * rstride, dn + c * 8 * 64);
    }

    const char* Kbase = (const char*)&KVs0[p][0];
    const char* Vbase = (const char*)&KVs1[p][0];

#pragma unroll
    for (int nt = 0; nt < 4; ++nt) {
      const char* rb = Kbase + (nt * 16 + l16) * 128;
      bf16x8 k0 = *(const bf16x8*)(rb + sw0);
      bf16x8 k1 = *(const bf16x8*)(rb + sw1);
#pragma unroll
      for (int qt = 0; qt < 2; ++qt) {
        f32x4 s = {};
        s = MFMA16(k0, qf[qt][0], s, 0, 0, 0);
        s = MFMA16(k1, qf[qt][1], s, 0, 0, 0);
        f32x4 pv;
#pragma unroll
        for (int e = 0; e < 4; ++e) pv[e] = __builtin_amdgcn_exp2f(s[e]);
        lac[qt] += pv;
        bf16x4 pb4;
#pragma unroll
        for (int e = 0; e < 4; ++e) pb4[e] = (bf16)pv[e];
        *(bf16x4*)&PqW[(qt * 16 + l16) * 72 + nt * 16 + quad * 4] = pb4;
      }
    }
    __asm__ volatile("s_waitcnt lgkmcnt(0)" ::: "memory");

#pragma unroll
    for (int ck = 0; ck < 2; ++ck) {
      bf16x8 bp0 = *(const bf16x8*)&PqW[(l16) * 72 + ck * 32 + quad * 8];
      bf16x8 bp1 = *(const bf16x8*)&PqW[(16 + l16) * 72 + ck * 32 + quad * 8];
      const int swc = ck ? sw1 : sw0;
#pragma unroll
      for (int dt = 0; dt < 4; ++dt) {
        bf16x8 av = *(const bf16x8*)(Vbase + (dt * 16 + l16) * 128 + swc);
        accO[dt][0] = MFMA16(av, bp0, accO[dt][0], 0, 0, 0);
        accO[dt][1] = MFMA16(av, bp1, accO[dt][1], 0, 0, 0);
      }
    }
  }

#pragma unroll
  for (int qt = 0; qt < 2; ++qt) {
    float lt = lac[qt][0] + lac[qt][1] + lac[qt][2] + lac[qt][3];
    lt += __shfl_xor(lt, 16);
    lt += __shfl_xor(lt, 32);
    if (lane < 16)
      lp[(size_t)(ks * 24 + bh) * SQQ + q0 + qt * 16 + l16] = lt;
#pragma unroll
    for (int dt = 0; dt < 4; ++dt) {
      bf16x4 ov;
#pragma unroll
      for (int r = 0; r < 4; ++r) ov[r] = (bf16)accO[dt][qt][r];
      *(bf16x4*)&Op[((size_t)(ks * 24 + bh) * SQQ + q0 + qt * 16 + l16) * HD + dt * 16 + quad * 4] = ov;
    }
  }
}

// -------------------------------------------------------------------------
// K4: merge 4 K-split partials -> Obb bf16 [b*1024+q][h*64+d], vec8
// -------------------------------------------------------------------------
__global__ __launch_bounds__(256) void k_merge(
    const bf16* __restrict__ Op, const float* __restrict__ lp,
    bf16* __restrict__ Ob)
{
  int t = blockIdx.x * 256 + threadIdx.x;          // 196608 total
  int d8 = t & 7, q = (t >> 3) & 1023, bh = t >> 13;
  float l = 0.f;
  float s[8] = {};
#pragma unroll
  for (int sp = 0; sp < 4; ++sp) {
    l += lp[(size_t)(sp * 24 + bh) * SQQ + q];
    bf16x8 v = *(const bf16x8*)&Op[((size_t)(sp * 24 + bh) * SQQ + q) * HD + d8 * 8];
#pragma unroll
    for (int e = 0; e < 8; ++e) s[e] += (float)v[e];
  }
  float inv = 1.0f / l;
  int b = bh / NH, h = bh - b * NH;
  bf16x8 o;
#pragma unroll
  for (int e = 0; e < 8; ++e) o[e] = (bf16)(s[e] * inv);
  *(bf16x8*)&Ob[((size_t)(b * SQQ + q)) * 384 + h * HD + d8 * 8] = o;
}

// -------------------------------------------------------------------------
// K5: proj GEMM, bf16 MFMA, swapped orientation -> f32x4 stores.
// Obb[4096x384] @ Wpt[384 n][384 k] + bias. Grid (32, 6), 128 thr.
// -------------------------------------------------------------------------
__global__ __launch_bounds__(128) void k_proj(
    const bf16* __restrict__ A, const bf16* __restrict__ Wt,
    const float* __restrict__ bias, float* __restrict__ out)
{
  __shared__ __attribute__((aligned(16))) bf16 As[128 * 40];
  __shared__ __attribute__((aligned(16))) bf16 Bs[64 * 40];
  const int tid = threadIdx.x;
  const int w = tid >> 6, lane = tid & 63, quad = lane >> 4, l16 = lane & 15;
  const int m0 = blockIdx.x * 128, n0 = blockIdx.y * 64;

  f32x4 acc[4][4] = {};

  for (int kc = 0; kc < 12; ++kc) {
    const int k0 = kc * 32;
    bf16x8 a4[4], b4[2];
#pragma unroll
    for (int c = 0; c < 4; ++c) {
      int ci = c * 128 + tid, rw = ci >> 2, c8 = ci & 3;
      a4[c] = *(const bf16x8*)&A[(size_t)(m0 + rw) * 384 + k0 + c8 * 8];
    }
#pragma unroll
    for (int c = 0; c < 2; ++c) {
      int ci = c * 128 + tid, rw = ci >> 2, c8 = ci & 3;
      b4[c] = *(const bf16x8*)&Wt[(size_t)(n0 + rw) * 384 + k0 + c8 * 8];
    }
    __syncthreads();
#pragma unroll
    for (int c = 0; c < 4; ++c) {
      int ci = c * 128 + tid, rw = ci >> 2, c8 = ci & 3;
      *(bf16x8*)&As[rw * 40 + c8 * 8] = a4[c];
    }
#pragma unroll
    for (int c = 0; c < 2; ++c) {
      int ci = c * 128 + tid, rw = ci >> 2, c8 = ci & 3;
      *(bf16x8*)&Bs[rw * 40 + c8 * 8] = b4[c];
    }
    __syncthreads();
    bf16x8 af[4], bw[4];
#pragma unroll
    for (int t = 0; t < 4; ++t) {
      af[t] = *(const bf16x8*)&As[(w * 64 + t * 16 + l16) * 40 + quad * 8];
      bw[t] = *(const bf16x8*)&Bs[(t * 16 + l16) * 40 + quad * 8];
    }
#pragma unroll
    for (int mt = 0; mt < 4; ++mt)
#pragma unroll
      for (int nt = 0; nt < 4; ++nt)
        acc[mt][nt] = MFMA16(bw[nt], af[mt], acc[mt][nt], 0, 0, 0);
  }

  f32x4 bv[4];
#pragma unroll
  for (int nt = 0; nt < 4; ++nt)
    bv[nt] = *(const f32x4*)&bias[n0 + nt * 16 + quad * 4];
#pragma unroll
  for (int mt = 0; mt < 4; ++mt) {
    int m = m0 + w * 64 + mt * 16 + l16;
#pragma unroll
    for (int nt = 0; nt < 4; ++nt) {
      f32x4 o = acc[mt][nt] + bv[nt];
      *(f32x4*)&out[(size_t)m * 384 + n0 + nt * 16 + quad * 4] = o;
    }
  }
}

// -------------------------------------------------------------------------
// ws layout (bytes):
//   Kb    @ 0         12582912   (qkv -> attn)
//   Vt    @ 12582912  12582912   (qkv -> attn)
//   Qp    @ 25165824   3145728   (qkv -> attn)
//   Wqt   @ 28311552    442368   (prep -> qkv)
//   Wpt   @ 28753920    294912   (prep -> proj)
//   lp    @ 29048832    393216   (attn -> merge)
//   Obb   @ 29442048   3145728   (merge -> proj)
//   Xb    @ 32587776   6291456   (prep -> qkv, dead after)
//   Opart @ 32587776  12582912   (attn -> merge; overlays Xb)
// total 45170688
// -------------------------------------------------------------------------
extern "C" void kernel_launch(void* const* d_in, const int* in_sizes, int n_in,
                              void* d_out, int out_size, void* d_ws, size_t ws_size,
                              hipStream_t stream)
{
  (void)in_sizes; (void)n_in; (void)out_size; (void)ws_size;
  const float* X  = (const float*)d_in[0];
  const float* Wq = (const float*)d_in[1];
  const float* qb = (const float*)d_in[2];
  const float* Wp = (const float*)d_in[3];
  const float* pb = (const float*)d_in[4];
  float* out = (float*)d_out;

  char* ws = (char*)d_ws;
  bf16*  Kb    = (bf16*)(ws);
  bf16*  Vt    = (bf16*)(ws + 12582912);
  bf16*  Qp    = (bf16*)(ws + 25165824);
  bf16*  Wqt   = (bf16*)(ws + 28311552);
  bf16*  Wpt   = (bf16*)(ws + 28753920);
  float* lpart = (float*)(ws + 29048832);
  bf16*  Obb   = (bf16*)(ws + 29442048);
  bf16*  Xb    = (bf16*)(ws + 32587776);
  bf16*  Opart = (bf16*)(ws + 32587776);   // overlays Xb (dead after k_qkv)

  k_prep <<<2976, 256, 0, stream>>>(X, Wq, Wp, Xb, Wqt, Wpt);
  k_qkv  <<<dim3(128, 18), 256, 0, stream>>>(Xb, Wqt, qb, Kb, Vt, Qp);
  k_attn <<<dim3(24, 8, 4), 256, 0, stream>>>(Qp, Kb, Vt, Opart, lpart);
  k_merge<<<768, 256, 0, stream>>>(Opart, lpart, Obb);
  k_proj <<<dim3(32, 6), 128, 0, stream>>>(Obb, Wpt, pb, out);
}

// Round 11
// 158.251 us; speedup vs baseline: 1.2856x; 1.0463x over previous
//
#include <hip/hip_runtime.h>

typedef __bf16 bf16;
typedef bf16 bf16x8 __attribute__((ext_vector_type(8)));
typedef bf16 bf16x4 __attribute__((ext_vector_type(4)));
typedef float f32x4 __attribute__((ext_vector_type(4)));

#define SEQ 4096
#define SQQ 1024
#define NH  6
#define HD  64

#define MFMA16 __builtin_amdgcn_mfma_f32_16x16x32_bf16

typedef const __attribute__((address_space(1))) void gvoid_t;
typedef __attribute__((address_space(3))) void svoid_t;

__device__ __forceinline__ void gload16(const bf16* g, bf16* l) {
  __builtin_amdgcn_global_load_lds((gvoid_t*)g, (svoid_t*)l, 16, 0, 0);
}

// -------------------------------------------------------------------------
// K0: prep (R11: LDS-tiled COALESCED transposes; old version did stride-4608B
// scattered f32 reads — one 64B line per 4B used).
//   blocks [0,216):    Wq [192][1152] -> Wqt bf16 [1152][192], 32x32 tiles
//   blocks [216,360):  Wp [384][384]  -> Wpt bf16 [384][384],  32x32 tiles
//   blocks [360,1896): X f32 -> Xb bf16 (vec8, coalesced)
// -------------------------------------------------------------------------
__global__ __launch_bounds__(256) void k_prep(
    const float* __restrict__ X, const float* __restrict__ Wq,
    const float* __restrict__ Wp,
    bf16* __restrict__ Xb, bf16* __restrict__ Wqt, bf16* __restrict__ Wpt)
{
  const int bid = blockIdx.x, tid = threadIdx.x;
  if (bid < 360) {
    __shared__ float tile[32][33];
    const float* src; bf16* dst; int k0, n0, sld, dld;
    if (bid < 216) {                   // Wq: k-rows 192, n-cols 1152
      int bn = bid % 36, bk = bid / 36;
      n0 = bn * 32; k0 = bk * 32;
      src = Wq; dst = Wqt; sld = 1152; dld = 192;
    } else {                           // Wp: 384 x 384
      int j = bid - 216;
      int bn = j % 12, bk = j / 12;
      n0 = bn * 32; k0 = bk * 32;
      src = Wp; dst = Wpt; sld = 384; dld = 384;
    }
    int c = tid & 31, r4 = tid >> 5;   // load: coalesced along n
#pragma unroll
    for (int i = 0; i < 4; ++i)
      tile[r4 * 4 + i][c] = src[(size_t)(k0 + r4 * 4 + i) * sld + n0 + c];
    __syncthreads();
    int r = tid & 31, c4 = tid >> 5;   // store: coalesced along k
#pragma unroll
    for (int i = 0; i < 4; ++i)
      dst[(size_t)(n0 + c4 * 4 + i) * dld + k0 + r] = (bf16)tile[r][c4 * 4 + i];
  } else {
    int v = (bid - 360) * 256 + tid;   // 393216 vec8 chunks
    f32x4 x0 = *(const f32x4*)&X[(size_t)v * 8];
    f32x4 x1 = *(const f32x4*)&X[(size_t)v * 8 + 4];
    bf16x8 h;
#pragma unroll
    for (int e = 0; e < 4; ++e) { h[e] = (bf16)x0[e]; h[4 + e] = (bf16)x1[e]; }
    *(bf16x8*)&Xb[(size_t)v * 8] = h;
  }
}

// -------------------------------------------------------------------------
// K1: QKV GEMM — R6-EXACT (proven <=42 us). bf16 MFMA, direct global
// fragments (L2-local), 128x128 tile, 2-deep register prefetch, zero
// in-loop barriers, natural register allocation (VGPR 132; R9 proved
// launch-bounds coercion => spill, R10 proved smaller n-tile => 2x loads).
// -------------------------------------------------------------------------
__global__ __launch_bounds__(256) void k_qkv(
    const bf16* __restrict__ Xb, const bf16* __restrict__ Wt,
    const float* __restrict__ bias,
    bf16* __restrict__ Kb, bf16* __restrict__ Vt, bf16* __restrict__ Qp)
{
  __shared__ __attribute__((aligned(16))) bf16 Qs[128 * 136];
  const int tid = threadIdx.x;
  const int w = tid >> 6, lane = tid & 63, quad = lane >> 4, l16 = lane & 15;
  const int wm = w & 1, wn = w >> 1;
  const int m0 = blockIdx.x * 128, n0 = blockIdx.y * 128;
  const int c3 = n0 / 384, nb = n0 - c3 * 384, b = m0 >> 12;

  const bf16* Arow = Xb + (size_t)(m0 + wm * 64 + l16) * 192 + quad * 8;
  const bf16* Brow = Wt + (size_t)(n0 + wn * 64 + l16) * 192 + quad * 8;

  f32x4 acc[4][4] = {};
  bf16x8 af[2][4], bw[2][4];
#pragma unroll
  for (int p = 0; p < 2; ++p)
#pragma unroll
    for (int t = 0; t < 4; ++t) {
      af[p][t] = *(const bf16x8*)(Arow + t * 16 * 192 + p * 32);
      bw[p][t] = *(const bf16x8*)(Brow + t * 16 * 192 + p * 32);
    }
#pragma unroll
  for (int kk = 0; kk < 6; ++kk) {
    const int s = kk & 1;
    if (c3 == 2) {
#pragma unroll
      for (int mt = 0; mt < 4; ++mt)
#pragma unroll
        for (int nt = 0; nt < 4; ++nt)
          acc[mt][nt] = MFMA16(af[s][mt], bw[s][nt], acc[mt][nt], 0, 0, 0);
    } else {
#pragma unroll
      for (int mt = 0; mt < 4; ++mt)
#pragma unroll
        for (int nt = 0; nt < 4; ++nt)
          acc[mt][nt] = MFMA16(bw[s][nt], af[s][mt], acc[mt][nt], 0, 0, 0);
    }
    if (kk < 4) {
      const int ko = (kk + 2) * 32;
#pragma unroll
      for (int t = 0; t < 4; ++t) {
        af[s][t] = *(const bf16x8*)(Arow + t * 16 * 192 + ko);
        bw[s][t] = *(const bf16x8*)(Brow + t * 16 * 192 + ko);
      }
    }
  }

  if (c3 == 2) {
    float bn[4];
#pragma unroll
    for (int nt = 0; nt < 4; ++nt) bn[nt] = bias[n0 + wn * 64 + nt * 16 + l16];
#pragma unroll
    for (int mt = 0; mt < 4; ++mt) {
      int sb = (m0 & 4095) + wm * 64 + mt * 16 + quad * 4;
#pragma unroll
      for (int nt = 0; nt < 4; ++nt) {
        int dcol = nb + wn * 64 + nt * 16 + l16;
        int h = dcol >> 6, dd = dcol & 63;
        bf16x4 pv;
#pragma unroll
        for (int r = 0; r < 4; ++r) pv[r] = (bf16)(acc[mt][nt][r] + bn[nt]);
        *(bf16x4*)&Vt[((size_t)(b * NH + h) * HD + dd) * SEQ + sb] = pv;
      }
    }
  } else if (c3 == 1) {
    f32x4 bv[4];
#pragma unroll
    for (int nt = 0; nt < 4; ++nt)
      bv[nt] = *(const f32x4*)&bias[n0 + wn * 64 + nt * 16 + quad * 4];
#pragma unroll
    for (int mt = 0; mt < 4; ++mt) {
      int s = (m0 & 4095) + wm * 64 + mt * 16 + l16;
#pragma unroll
      for (int nt = 0; nt < 4; ++nt) {
        int ncol = nb + wn * 64 + nt * 16 + quad * 4;
        int h = ncol >> 6, dd = ncol & 63;
        bf16x4 pv;
#pragma unroll
        for (int r = 0; r < 4; ++r) pv[r] = (bf16)(acc[mt][nt][r] + bv[nt][r]);
        *(bf16x4*)&Kb[((size_t)(b * NH + h) * SEQ + s) * HD + dd] = pv;
      }
    }
  } else {
    f32x4 bv[4];
#pragma unroll
    for (int nt = 0; nt < 4; ++nt)
      bv[nt] = *(const f32x4*)&bias[n0 + wn * 64 + nt * 16 + quad * 4];
#pragma unroll
    for (int mt = 0; mt < 4; ++mt) {
      int ml = wm * 64 + mt * 16 + l16;
#pragma unroll
      for (int nt = 0; nt < 4; ++nt) {
        int ncl = wn * 64 + nt * 16 + quad * 4;
        bf16x4 pv;
#pragma unroll
        for (int r = 0; r < 4; ++r) pv[r] = (bf16)(acc[mt][nt][r] + bv[nt][r]);
        *(bf16x4*)&Qs[ml * 136 + ncl] = pv;
      }
    }
    __syncthreads();
    const int wq = tid >> 3, cg = tid & 7;
    const int hq = (m0 & 4095) >> 7;
#pragma unroll
    for (int j8 = 0; j8 < 2; ++j8) {
      int co = cg * 16 + j8 * 8;
      bf16x8 q0 = *(const bf16x8*)&Qs[(2 * wq)     * 136 + co];
      bf16x8 q1 = *(const bf16x8*)&Qs[(2 * wq + 1) * 136 + co];
      bf16x8 q2 = *(const bf16x8*)&Qs[(64 + 2 * wq)     * 136 + co];
      bf16x8 q3 = *(const bf16x8*)&Qs[(64 + 2 * wq + 1) * 136 + co];
      bf16x8 o;
#pragma unroll
      for (int e = 0; e < 8; ++e) {
        float mx = fmaxf(fmaxf((float)q0[e], (float)q1[e]),
                         fmaxf((float)q2[e], (float)q3[e]));
        o[e] = (bf16)(mx * 0.180336880111f);   // 0.125 * log2(e)
      }
      int gc = nb + co;
      int h = gc >> 6, d0 = gc & 63;
      *(bf16x8*)&Qp[((size_t)(b * NH + h) * SQQ + hq * 32 + wq) * HD + d0] = o;
    }
  }
}

// -------------------------------------------------------------------------
// K3: attention — R6-EXACT (proven 42.6 us): 4 waves/block, 32 q/wave,
// double-buffered KV LDS via global_load_lds, XOR-swizzled conflict-free
// reads, S^T=K.Q^T, no max-stabilization, K-split 4. Grid (24, 8, 4), 256 thr.
// -------------------------------------------------------------------------
__global__ __launch_bounds__(256) void k_attn(
    const bf16* __restrict__ Qp, const bf16* __restrict__ Kb,
    const bf16* __restrict__ Vt, bf16* __restrict__ Op, float* __restrict__ lp)
{
  __shared__ __attribute__((aligned(16))) bf16 KVs0[2][64 * 64];  // K [kpos][d^]
  __shared__ __attribute__((aligned(16))) bf16 KVs1[2][64 * 64];  // V^T [d][kpos^]
  __shared__ __attribute__((aligned(16))) bf16 Pq[4][32 * 72];    // per-wave P

  const int tid = threadIdx.x;
  const int w = tid >> 6, lane = tid & 63, quad = lane >> 4, l16 = lane & 15;
  const int bh = blockIdx.x, qb = blockIdx.y, ks = blockIdx.z;
  const int q0 = qb * 128 + w * 32;

  const bf16* Qg = Qp + (size_t)bh * SQQ * HD;
  const bf16* Kg = Kb + (size_t)bh * SEQ * HD;
  const bf16* Vg = Vt + (size_t)bh * HD * SEQ;

  bf16x8 qf[2][2];
#pragma unroll
  for (int qt = 0; qt < 2; ++qt)
#pragma unroll
    for (int dk = 0; dk < 2; ++dk)
      qf[qt][dk] = *(const bf16x8*)&Qg[(size_t)(q0 + qt * 16 + l16) * HD + dk * 32 + quad * 8];

  const int swz = l16 & 7;
  const int sw0 = ((quad ^ swz) * 16);
  const int sw1 = (((quad + 4) ^ swz) * 16);
  const int sr = lane >> 3;          // 0..7
  const int sc = (lane & 7) ^ sr;    // XOR-permuted source chunk

  const bf16* src;
  bf16 *dstA, *dstB;
  size_t rstride, step;
  if (w < 2) {
    src = Kg + (size_t)(ks * 1024 + w * 32 + sr) * HD + sc * 8;
    dstA = &KVs0[0][(w * 32) * 64];
    dstB = &KVs0[1][(w * 32) * 64];
    rstride = 8 * HD;  step = 64 * HD;
  } else {
    src = Vg + (size_t)((w - 2) * 32 + sr) * SEQ + ks * 1024 + sc * 8;
    dstA = &KVs1[0][((w - 2) * 32) * 64];
    dstB = &KVs1[1][((w - 2) * 32) * 64];
    rstride = 8 * SEQ; step = 64;
  }

#pragma unroll
  for (int c = 0; c < 4; ++c) gload16(src + c * rstride, dstA + c * 8 * 64);

  f32x4 lac[2] = {};
  f32x4 accO[4][2] = {};
  bf16* PqW = &Pq[w][0];

  for (int it = 0; it < 16; ++it) {
    const int p = it & 1;
    __asm__ volatile("s_waitcnt vmcnt(0)" ::: "memory");
    __syncthreads();
    if (it < 15) {
      const bf16* s2 = src + (size_t)(it + 1) * step;
      bf16* dn = p ? dstA : dstB;
#pragma unroll
      for (int c = 0; c < 4; ++c) gload16(s2 + c * rstride, dn + c * 8 * 64);
    }

    const char* Kbase = (const char*)&KVs0[p][0];
    const char* Vbase = (const char*)&KVs1[p][0];

#pragma unroll
    for (int nt = 0; nt < 4; ++nt) {
      const char* rb = Kbase + (nt * 16 + l16) * 128;
      bf16x8 k0 = *(const bf16x8*)(rb + sw0);
      bf16x8 k1 = *(const bf16x8*)(rb + sw1);
#pragma unroll
      for (int qt = 0; qt < 2; ++qt) {
        f32x4 s = {};
        s = MFMA16(k0, qf[qt][0], s, 0, 0, 0);
        s = MFMA16(k1, qf[qt][1], s, 0, 0, 0);
        f32x4 pv;
#pragma unroll
        for (int e = 0; e < 4; ++e) pv[e] = __builtin_amdgcn_exp2f(s[e]);
        lac[qt] += pv;
        bf16x4 pb4;
#pragma unroll
        for (int e = 0; e < 4; ++e) pb4[e] = (bf16)pv[e];
        *(bf16x4*)&PqW[(qt * 16 + l16) * 72 + nt * 16 + quad * 4] = pb4;
      }
    }
    __asm__ volatile("s_waitcnt lgkmcnt(0)" ::: "memory");

#pragma unroll
    for (int ck = 0; ck < 2; ++ck) {
      bf16x8 bp0 = *(const bf16x8*)&PqW[(l16) * 72 + ck * 32 + quad * 8];
      bf16x8 bp1 = *(const bf16x8*)&PqW[(16 + l16) * 72 + ck * 32 + quad * 8];
      const int swc = ck ? sw1 : sw0;
#pragma unroll
      for (int dt = 0; dt < 4; ++dt) {
        bf16x8 av = *(const bf16x8*)(Vbase + (dt * 16 + l16) * 128 + swc);
        accO[dt][0] = MFMA16(av, bp0, accO[dt][0], 0, 0, 0);
        accO[dt][1] = MFMA16(av, bp1, accO[dt][1], 0, 0, 0);
      }
    }
  }

#pragma unroll
  for (int qt = 0; qt < 2; ++qt) {
    float lt = lac[qt][0] + lac[qt][1] + lac[qt][2] + lac[qt][3];
    lt += __shfl_xor(lt, 16);
    lt += __shfl_xor(lt, 32);
    if (lane < 16)
      lp[(size_t)(ks * 24 + bh) * SQQ + q0 + qt * 16 + l16] = lt;
#pragma unroll
    for (int dt = 0; dt < 4; ++dt) {
      bf16x4 ov;
#pragma unroll
      for (int r = 0; r < 4; ++r) ov[r] = (bf16)accO[dt][qt][r];
      *(bf16x4*)&Op[((size_t)(ks * 24 + bh) * SQQ + q0 + qt * 16 + l16) * HD + dt * 16 + quad * 4] = ov;
    }
  }
}

// -------------------------------------------------------------------------
// K4: merge 4 K-split partials -> Obb bf16 [b*1024+q][h*64+d], vec8
// -------------------------------------------------------------------------
__global__ __launch_bounds__(256) void k_merge(
    const bf16* __restrict__ Op, const float* __restrict__ lp,
    bf16* __restrict__ Ob)
{
  int t = blockIdx.x * 256 + threadIdx.x;          // 196608 total
  int d8 = t & 7, q = (t >> 3) & 1023, bh = t >> 13;
  float l = 0.f;
  float s[8] = {};
#pragma unroll
  for (int sp = 0; sp < 4; ++sp) {
    l += lp[(size_t)(sp * 24 + bh) * SQQ + q];
    bf16x8 v = *(const bf16x8*)&Op[((size_t)(sp * 24 + bh) * SQQ + q) * HD + d8 * 8];
#pragma unroll
    for (int e = 0; e < 8; ++e) s[e] += (float)v[e];
  }
  float inv = 1.0f / l;
  int b = bh / NH, h = bh - b * NH;
  bf16x8 o;
#pragma unroll
  for (int e = 0; e < 8; ++e) o[e] = (bf16)(s[e] * inv);
  *(bf16x8*)&Ob[((size_t)(b * SQQ + q)) * 384 + h * HD + d8 * 8] = o;
}

// -------------------------------------------------------------------------
// K5: proj GEMM, bf16 MFMA, swapped orientation -> f32x4 stores.
// Obb[4096x384] @ Wpt[384 n][384 k] + bias. Grid (32, 6), 128 thr.
// -------------------------------------------------------------------------
__global__ __launch_bounds__(128) void k_proj(
    const bf16* __restrict__ A, const bf16* __restrict__ Wt,
    const float* __restrict__ bias, float* __restrict__ out)
{
  __shared__ __attribute__((aligned(16))) bf16 As[128 * 40];
  __shared__ __attribute__((aligned(16))) bf16 Bs[64 * 40];
  const int tid = threadIdx.x;
  const int w = tid >> 6, lane = tid & 63, quad = lane >> 4, l16 = lane & 15;
  const int m0 = blockIdx.x * 128, n0 = blockIdx.y * 64;

  f32x4 acc[4][4] = {};

  for (int kc = 0; kc < 12; ++kc) {
    const int k0 = kc * 32;
    bf16x8 a4[4], b4[2];
#pragma unroll
    for (int c = 0; c < 4; ++c) {
      int ci = c * 128 + tid, rw = ci >> 2, c8 = ci & 3;
      a4[c] = *(const bf16x8*)&A[(size_t)(m0 + rw) * 384 + k0 + c8 * 8];
    }
#pragma unroll
    for (int c = 0; c < 2; ++c) {
      int ci = c * 128 + tid, rw = ci >> 2, c8 = ci & 3;
      b4[c] = *(const bf16x8*)&Wt[(size_t)(n0 + rw) * 384 + k0 + c8 * 8];
    }
    __syncthreads();
#pragma unroll
    for (int c = 0; c < 4; ++c) {
      int ci = c * 128 + tid, rw = ci >> 2, c8 = ci & 3;
      *(bf16x8*)&As[rw * 40 + c8 * 8] = a4[c];
    }
#pragma unroll
    for (int c = 0; c < 2; ++c) {
      int ci = c * 128 + tid, rw = ci >> 2, c8 = ci & 3;
      *(bf16x8*)&Bs[rw * 40 + c8 * 8] = b4[c];
    }
    __syncthreads();
    bf16x8 af[4], bw[4];
#pragma unroll
    for (int t = 0; t < 4; ++t) {
      af[t] = *(const bf16x8*)&As[(w * 64 + t * 16 + l16) * 40 + quad * 8];
      bw[t] = *(const bf16x8*)&Bs[(t * 16 + l16) * 40 + quad * 8];
    }
#pragma unroll
    for (int mt = 0; mt < 4; ++mt)
#pragma unroll
      for (int nt = 0; nt < 4; ++nt)
        acc[mt][nt] = MFMA16(bw[nt], af[mt], acc[mt][nt], 0, 0, 0);
  }

  f32x4 bv[4];
#pragma unroll
  for (int nt = 0; nt < 4; ++nt)
    bv[nt] = *(const f32x4*)&bias[n0 + nt * 16 + quad * 4];
#pragma unroll
  for (int mt = 0; mt < 4; ++mt) {
    int m = m0 + w * 64 + mt * 16 + l16;
#pragma unroll
    for (int nt = 0; nt < 4; ++nt) {
      f32x4 o = acc[mt][nt] + bv[nt];
      *(f32x4*)&out[(size_t)m * 384 + n0 + nt * 16 + quad * 4] = o;
    }
  }
}

// -------------------------------------------------------------------------
// ws layout (bytes):
//   Kb    @ 0         12582912   (qkv -> attn)
//   Vt    @ 12582912  12582912   (qkv -> attn)
//   Qp    @ 25165824   3145728   (qkv -> attn)
//   Wqt   @ 28311552    442368   (prep -> qkv)
//   Wpt   @ 28753920    294912   (prep -> proj)
//   lp    @ 29048832    393216   (attn -> merge)
//   Obb   @ 29442048   3145728   (merge -> proj)
//   Xb    @ 32587776   6291456   (prep -> qkv, dead after)
//   Opart @ 32587776  12582912   (attn -> merge; overlays Xb)
// total 45170688
// -------------------------------------------------------------------------
extern "C" void kernel_launch(void* const* d_in, const int* in_sizes, int n_in,
                              void* d_out, int out_size, void* d_ws, size_t ws_size,
                              hipStream_t stream)
{
  (void)in_sizes; (void)n_in; (void)out_size; (void)ws_size;
  const float* X  = (const float*)d_in[0];
  const float* Wq = (const float*)d_in[1];
  const float* qb = (const float*)d_in[2];
  const float* Wp = (const float*)d_in[3];
  const float* pb = (const float*)d_in[4];
  float* out = (float*)d_out;

  char* ws = (char*)d_ws;
  bf16*  Kb    = (bf16*)(ws);
  bf16*  Vt    = (bf16*)(ws + 12582912);
  bf16*  Qp    = (bf16*)(ws + 25165824);
  bf16*  Wqt   = (bf16*)(ws + 28311552);
  bf16*  Wpt   = (bf16*)(ws + 28753920);
  float* lpart = (float*)(ws + 29048832);
  bf16*  Obb   = (bf16*)(ws + 29442048);
  bf16*  Xb    = (bf16*)(ws + 32587776);
  bf16*  Opart = (bf16*)(ws + 32587776);   // overlays Xb (dead after k_qkv)

  k_prep <<<1896, 256, 0, stream>>>(X, Wq, Wp, Xb, Wqt, Wpt);
  k_qkv  <<<dim3(128, 9), 256, 0, stream>>>(Xb, Wqt, qb, Kb, Vt, Qp);
  k_attn <<<dim3(24, 8, 4), 256, 0, stream>>>(Qp, Kb, Vt, Opart, lpart);
  k_merge<<<768, 256, 0, stream>>>(Opart, lpart, Obb);
  k_proj <<<dim3(32, 6), 128, 0, stream>>>(Obb, Wpt, pb, out);
}